// Round 4
// baseline (1846.162 us; speedup 1.0000x reference)
//
#include <hip/hip_runtime.h>
#include <hip/hip_bf16.h>
#include <hip/hip_fp16.h>

#define N_NODES 100000
#define N_EDGES 1600000
#define HEADS 4
#define CHN 32
#define HID 128
#define LAYERS 4
#define IN_F 8
#define ED_F 6
#define OUT_F 256
#define NEG_SLOPE 0.2f

__device__ __forceinline__ float elu_f(float x) {
    return x > 0.f ? x : expm1f(x);
}

// ---------------- CSR build ----------------

__global__ void hist_kernel(const int* __restrict__ dst, int* __restrict__ fill) {
    int e = blockIdx.x * blockDim.x + threadIdx.x;
    if (e < N_EDGES) atomicAdd(&fill[dst[e]], 1);
}

__global__ void scan1_kernel(const int* __restrict__ cnt, int* __restrict__ bsum) {
    __shared__ int sd[256];
    int t = threadIdx.x;
    int base = blockIdx.x * 1024 + t * 4;
    int s = 0;
#pragma unroll
    for (int j = 0; j < 4; ++j) {
        int i = base + j;
        if (i < N_NODES) s += cnt[i];
    }
    sd[t] = s;
    for (int off = 128; off > 0; off >>= 1) {
        __syncthreads();
        if (t < off) sd[t] += sd[t + off];
    }
    if (t == 0) bsum[blockIdx.x] = sd[0];
}

__global__ void scan2_kernel(int* __restrict__ bsum, int* __restrict__ rowptr, int nb) {
    int run = 0;
    for (int b = 0; b < nb; ++b) {
        int v = bsum[b];
        bsum[b] = run;
        run += v;
    }
    rowptr[N_NODES] = run;
}

__global__ void scan3_kernel(const int* __restrict__ cnt, const int* __restrict__ bsum,
                             int* __restrict__ rowptr) {
    __shared__ int sd[256];
    int t = threadIdx.x;
    int base = blockIdx.x * 1024 + t * 4;
    int v[4];
#pragma unroll
    for (int j = 0; j < 4; ++j) {
        int i = base + j;
        v[j] = (i < N_NODES) ? cnt[i] : 0;
    }
    int s = v[0] + v[1] + v[2] + v[3];
    sd[t] = s;
    __syncthreads();
    for (int off = 1; off < 256; off <<= 1) {
        int xv = (t >= off) ? sd[t - off] : 0;
        __syncthreads();
        sd[t] += xv;
        __syncthreads();
    }
    int excl = sd[t] - s + bsum[blockIdx.x];
    int pre = 0;
#pragma unroll
    for (int j = 0; j < 4; ++j) {
        int i = base + j;
        if (i < N_NODES) rowptr[i] = excl + pre;
        pre += v[j];
    }
}

__global__ void fill_kernel(const int* __restrict__ src, const int* __restrict__ dst,
                            const int* __restrict__ rowptr, int* __restrict__ fill,
                            int2* __restrict__ csr) {
    int e = blockIdx.x * blockDim.x + threadIdx.x;
    if (e >= N_EDGES) return;
    int d = dst[e];
    int p = rowptr[d] + atomicAdd(&fill[d], 1);
    csr[p] = make_int2(src[e], e);
}

// loop_attr = mean of incoming edge_attr per node (0 if no incoming edges)
__global__ void lattr_kernel(const int* __restrict__ rowptr, const int2* __restrict__ csr,
                             const float* __restrict__ eattr, float* __restrict__ lattr) {
    int gid = blockIdx.x * blockDim.x + threadIdx.x;
    if (gid >= N_NODES * ED_F) return;
    int n = gid / ED_F;
    int d = gid - n * ED_F;
    int rp0 = rowptr[n], rp1 = rowptr[n + 1];
    float s = 0.f;
    for (int p = rp0; p < rp1; ++p) s += eattr[(size_t)csr[p].y * ED_F + d];
    int deg = rp1 - rp0;
    lattr[gid] = s / (float)(deg > 0 ? deg : 1);
}

// ---------------- input MLP: h0 = ELU(x @ W_in + b_in) ----------------

__global__ void in_kernel(const float* __restrict__ x, const float* __restrict__ Wi,
                          const float* __restrict__ bi, float* __restrict__ h0) {
    int gid = blockIdx.x * blockDim.x + threadIdx.x;
    if (gid >= N_NODES * HID) return;
    int n = gid >> 7, j = gid & 127;
    float acc = bi[j];
#pragma unroll
    for (int k = 0; k < IN_F; ++k) acc = fmaf(x[n * IN_F + k], Wi[k * HID + j], acc);
    h0[gid] = elu_f(acc);
}

// ---------------- per-layer node transforms xl = h@Wl+bl (f16), xr = h@Wr+br (f32) ----------------

__global__ __launch_bounds__(128) void xlr_kernel(
    const float* __restrict__ h, const float* __restrict__ Wl, const float* __restrict__ bl,
    const float* __restrict__ Wr, const float* __restrict__ br,
    __half* __restrict__ xl, float* __restrict__ xr) {
    __shared__ float hs[16][HID];
    int t = threadIdx.x;
    int r0 = blockIdx.x * 16;
#pragma unroll
    for (int r = 0; r < 16; ++r) hs[r][t] = h[(size_t)(r0 + r) * HID + t];
    __syncthreads();
    float accl[16], accr[16];
    float blv = bl[t], brv = br[t];
#pragma unroll
    for (int r = 0; r < 16; ++r) { accl[r] = blv; accr[r] = brv; }
    for (int k = 0; k < HID; ++k) {
        float wl = Wl[k * HID + t];
        float wr = Wr[k * HID + t];
#pragma unroll
        for (int r = 0; r < 16; ++r) {
            float hv = hs[r][k];
            accl[r] = fmaf(hv, wl, accl[r]);
            accr[r] = fmaf(hv, wr, accr[r]);
        }
    }
#pragma unroll
    for (int r = 0; r < 16; ++r) {
        xl[(size_t)(r0 + r) * HID + t] = __float2half_rn(accl[r]);
        xr[(size_t)(r0 + r) * HID + t] = accr[r];
    }
}

// ---------------- fused edge kernel: single-pass softmax-aggregate + LN ----------------
// 4 nodes per 256-thread block; one wave per node; lane l owns channels 2l, 2l+1.
// out = (sum_e ex_e * xl[src_e]) / (sum_e ex_e)  -- identical to two-pass softmax
// since no max-subtraction is needed (scores bounded, f32 exp safe).

__device__ __forceinline__ float edge_ex(const float* __restrict__ eat,
                                         const __half2* __restrict__ xlrow,
                                         const float* we0, const float* we1,
                                         float at0, float at1, float xr0, float xr1,
                                         float2* xls_out) {
    float ea0 = 0.f, ea1 = 0.f;
#pragma unroll
    for (int d = 0; d < ED_F; ++d) {
        float a = eat[d];
        ea0 = fmaf(a, we0[d], ea0);
        ea1 = fmaf(a, we1[d], ea1);
    }
    float2 xls = __half22float2(*xlrow);
    float m0 = xls.x + xr0 + ea0;
    float m1 = xls.y + xr1 + ea1;
    m0 = m0 > 0.f ? m0 : NEG_SLOPE * m0;
    m1 = m1 > 0.f ? m1 : NEG_SLOPE * m1;
    float t = m0 * at0 + m1 * at1;
    // reduce across the 16 lanes of this head (32 channels)
    t += __shfl_xor(t, 1);
    t += __shfl_xor(t, 2);
    t += __shfl_xor(t, 4);
    t += __shfl_xor(t, 8);
    *xls_out = xls;
    return __expf(t);
}

__global__ __launch_bounds__(256) void edge_kernel(
    const __half* __restrict__ xl, const float* __restrict__ xr,
    const float* __restrict__ hcur, float* __restrict__ hnext,
    const int* __restrict__ rowptr, const int2* __restrict__ csr,
    const float* __restrict__ eattr, const float* __restrict__ lattr,
    const float* __restrict__ We, const float* __restrict__ att,
    const float* __restrict__ bias_l, const float* __restrict__ lnw,
    const float* __restrict__ lnb) {
    int v = blockIdx.x * 4 + (threadIdx.x >> 6);
    int lane = threadIdx.x & 63;
    int c0 = lane * 2;

    float we0[ED_F], we1[ED_F];
#pragma unroll
    for (int d = 0; d < ED_F; ++d) {
        we0[d] = We[d * HID + c0];
        we1[d] = We[d * HID + c0 + 1];
    }
    float at0 = att[c0], at1 = att[c0 + 1];
    float xr0 = xr[(size_t)v * HID + c0];
    float xr1 = xr[(size_t)v * HID + c0 + 1];
    int rp0 = rowptr[v], rp1 = rowptr[v + 1];

    // single pass: numerator (acc) and denominator together
    float2 xlv;
    float ex_self = edge_ex(lattr + (size_t)v * ED_F,
                            (const __half2*)(xl + (size_t)v * HID + c0),
                            we0, we1, at0, at1, xr0, xr1, &xlv);
    float denom = ex_self;
    float acc0 = ex_self * xlv.x;
    float acc1 = ex_self * xlv.y;
    for (int p = rp0; p < rp1; ++p) {
        int2 se = csr[p];
        float2 xls;
        float ex = edge_ex(eattr + (size_t)se.y * ED_F,
                           (const __half2*)(xl + (size_t)se.x * HID + c0),
                           we0, we1, at0, at1, xr0, xr1, &xls);
        denom += ex;
        acc0 = fmaf(ex, xls.x, acc0);
        acc1 = fmaf(ex, xls.y, acc1);
    }
    float rd = 1.f / denom;
    acc0 *= rd;
    acc1 *= rd;

    // ---- epilogue: bias + residual + LayerNorm + ELU
    float res0 = hcur[(size_t)v * HID + c0];
    float res1 = hcur[(size_t)v * HID + c0 + 1];
    float y0 = acc0 + bias_l[c0] + res0;
    float y1 = acc1 + bias_l[c0 + 1] + res1;
    float s = y0 + y1;
    float sq = y0 * y0 + y1 * y1;
#pragma unroll
    for (int off = 1; off < 64; off <<= 1) {
        s += __shfl_xor(s, off);
        sq += __shfl_xor(sq, off);
    }
    float mu = s * (1.f / HID);
    float var = sq * (1.f / HID) - mu * mu;
    float rstd = rsqrtf(var + 1e-5f);
    float n0 = (y0 - mu) * rstd * lnw[c0] + lnb[c0];
    float n1 = (y1 - mu) * rstd * lnw[c0 + 1] + lnb[c0 + 1];
    float2 o;
    o.x = elu_f(n0);
    o.y = elu_f(n1);
    *(float2*)(hnext + (size_t)v * HID + c0) = o;
}

// ---------------- output GEMM: out = h @ W_out + b_out ----------------

__global__ __launch_bounds__(256) void out_kernel(const float* __restrict__ h,
                                                  const float* __restrict__ Wo,
                                                  const float* __restrict__ bo,
                                                  float* __restrict__ out) {
    __shared__ float hs[16][HID];
    int t = threadIdx.x;
    int r0 = blockIdx.x * 16;
    for (int idx = t; idx < 16 * HID; idx += 256)
        hs[idx >> 7][idx & 127] = h[(size_t)r0 * HID + idx];
    __syncthreads();
    float acc[16];
    float bv = bo[t];
#pragma unroll
    for (int r = 0; r < 16; ++r) acc[r] = bv;
    for (int k = 0; k < HID; ++k) {
        float w = Wo[k * OUT_F + t];
#pragma unroll
        for (int r = 0; r < 16; ++r) acc[r] = fmaf(hs[r][k], w, acc[r]);
    }
#pragma unroll
    for (int r = 0; r < 16; ++r) out[(size_t)(r0 + r) * OUT_F + t] = acc[r];
}

// ---------------- launch ----------------

extern "C" void kernel_launch(void* const* d_in, const int* in_sizes, int n_in,
                              void* d_out, int out_size, void* d_ws, size_t ws_size,
                              hipStream_t stream) {
    const float* x     = (const float*)d_in[0];
    const int*   ei    = (const int*)d_in[1];
    const float* eattr = (const float*)d_in[2];
    const float* W_in  = (const float*)d_in[3];
    const float* b_in  = (const float*)d_in[4];
    const float* W_l   = (const float*)d_in[5];
    const float* b_l   = (const float*)d_in[6];
    const float* W_r   = (const float*)d_in[7];
    const float* b_r   = (const float*)d_in[8];
    const float* W_e   = (const float*)d_in[9];
    const float* att   = (const float*)d_in[10];
    const float* bias  = (const float*)d_in[11];
    const float* lnw   = (const float*)d_in[12];
    const float* lnb   = (const float*)d_in[13];
    const float* W_out = (const float*)d_in[14];
    const float* b_out = (const float*)d_in[15];
    float* out = (float*)d_out;

    // workspace layout
    float* h0    = (float*)d_ws;
    float* h1    = h0 + (size_t)N_NODES * HID;
    float* lattr = h1 + (size_t)N_NODES * HID;
    int* rowptr  = (int*)(lattr + (size_t)N_NODES * ED_F);
    int* fill    = rowptr + (N_NODES + 1);
    int2* csr    = (int2*)(fill + N_NODES);
    int* bsum    = (int*)(csr + N_EDGES);

    // reuse d_out (N x 256 f32) as scratch: xr f32 (N x 128), xl f16 (N x 128);
    // out_kernel fully overwrites it at the end.
    float*  xr = out;
    __half* xl = (__half*)(out + (size_t)N_NODES * HID);

    const int* srcv = ei;
    const int* dstv = ei + N_EDGES;

    hipMemsetAsync(fill, 0, N_NODES * sizeof(int), stream);
    hist_kernel<<<(N_EDGES + 255) / 256, 256, 0, stream>>>(dstv, fill);
    int nb = (N_NODES + 1023) / 1024;
    scan1_kernel<<<nb, 256, 0, stream>>>(fill, bsum);
    scan2_kernel<<<1, 1, 0, stream>>>(bsum, rowptr, nb);
    scan3_kernel<<<nb, 256, 0, stream>>>(fill, bsum, rowptr);
    hipMemsetAsync(fill, 0, N_NODES * sizeof(int), stream);
    fill_kernel<<<(N_EDGES + 255) / 256, 256, 0, stream>>>(srcv, dstv, rowptr, fill, csr);
    lattr_kernel<<<(N_NODES * ED_F + 255) / 256, 256, 0, stream>>>(rowptr, csr, eattr, lattr);

    in_kernel<<<(N_NODES * HID) / 256, 256, 0, stream>>>(x, W_in, b_in, h0);

    float* hc = h0;
    float* hn = h1;
    for (int l = 0; l < LAYERS; ++l) {
        xlr_kernel<<<N_NODES / 16, 128, 0, stream>>>(
            hc, W_l + (size_t)l * HID * HID, b_l + (size_t)l * HID,
            W_r + (size_t)l * HID * HID, b_r + (size_t)l * HID, xl, xr);
        edge_kernel<<<N_NODES / 4, 256, 0, stream>>>(
            xl, xr, hc, hn, rowptr, csr, eattr, lattr,
            W_e + (size_t)l * ED_F * HID, att + (size_t)l * HEADS * CHN,
            bias + (size_t)l * HID, lnw + (size_t)l * HID, lnb + (size_t)l * HID);
        float* tmp = hc; hc = hn; hn = tmp;
    }

    out_kernel<<<N_NODES / 16, 256, 0, stream>>>(hc, W_out, b_out, out);
}

// Round 6
// 1454.703 us; speedup vs baseline: 1.2691x; 1.2691x over previous
//
#include <hip/hip_runtime.h>
#include <hip/hip_bf16.h>
#include <hip/hip_fp16.h>

#define N_NODES 100000
#define N_EDGES 1600000
#define HEADS 4
#define CHN 32
#define HID 128
#define LAYERS 4
#define IN_F 8
#define ED_F 6
#define OUT_F 256
#define NEG_SLOPE 0.2f

__device__ __forceinline__ float elu_f(float x) {
    return x > 0.f ? x : expm1f(x);
}

// ---------------- CSR build ----------------

__global__ void hist_kernel(const int* __restrict__ dst, int* __restrict__ fill) {
    int e = blockIdx.x * blockDim.x + threadIdx.x;
    if (e < N_EDGES) atomicAdd(&fill[dst[e]], 1);
}

__global__ void scan1_kernel(const int* __restrict__ cnt, int* __restrict__ bsum) {
    __shared__ int sd[256];
    int t = threadIdx.x;
    int base = blockIdx.x * 1024 + t * 4;
    int s = 0;
#pragma unroll
    for (int j = 0; j < 4; ++j) {
        int i = base + j;
        if (i < N_NODES) s += cnt[i];
    }
    sd[t] = s;
    for (int off = 128; off > 0; off >>= 1) {
        __syncthreads();
        if (t < off) sd[t] += sd[t + off];
    }
    if (t == 0) bsum[blockIdx.x] = sd[0];
}

__global__ void scan2_kernel(int* __restrict__ bsum, int* __restrict__ rowptr, int nb) {
    int run = 0;
    for (int b = 0; b < nb; ++b) {
        int v = bsum[b];
        bsum[b] = run;
        run += v;
    }
    rowptr[N_NODES] = run;
}

__global__ void scan3_kernel(const int* __restrict__ cnt, const int* __restrict__ bsum,
                             int* __restrict__ rowptr) {
    __shared__ int sd[256];
    int t = threadIdx.x;
    int base = blockIdx.x * 1024 + t * 4;
    int v[4];
#pragma unroll
    for (int j = 0; j < 4; ++j) {
        int i = base + j;
        v[j] = (i < N_NODES) ? cnt[i] : 0;
    }
    int s = v[0] + v[1] + v[2] + v[3];
    sd[t] = s;
    __syncthreads();
    for (int off = 1; off < 256; off <<= 1) {
        int xv = (t >= off) ? sd[t - off] : 0;
        __syncthreads();
        sd[t] += xv;
        __syncthreads();
    }
    int excl = sd[t] - s + bsum[blockIdx.x];
    int pre = 0;
#pragma unroll
    for (int j = 0; j < 4; ++j) {
        int i = base + j;
        if (i < N_NODES) rowptr[i] = excl + pre;
        pre += v[j];
    }
}

// csr stores BYTE offsets: x = src*HID*2 (f16 row), y = eid*ED_F*4
__global__ void fill_kernel(const int* __restrict__ src, const int* __restrict__ dst,
                            const int* __restrict__ rowptr, int* __restrict__ fill,
                            int2* __restrict__ csr) {
    int e = blockIdx.x * blockDim.x + threadIdx.x;
    if (e >= N_EDGES) return;
    int d = dst[e];
    int p = rowptr[d] + atomicAdd(&fill[d], 1);
    csr[p] = make_int2(src[e] * (HID * 2), e * (ED_F * 4));
}

// loop_attr = mean of incoming edge_attr per node (0 if no incoming edges)
__global__ void lattr_kernel(const int* __restrict__ rowptr, const int2* __restrict__ csr,
                             const float* __restrict__ eattr, float* __restrict__ lattr) {
    int gid = blockIdx.x * blockDim.x + threadIdx.x;
    if (gid >= N_NODES * ED_F) return;
    int n = gid / ED_F;
    int d = gid - n * ED_F;
    int rp0 = rowptr[n], rp1 = rowptr[n + 1];
    float s = 0.f;
    for (int p = rp0; p < rp1; ++p)
        s += *(const float*)((const char*)eattr + (size_t)csr[p].y + d * 4);
    int deg = rp1 - rp0;
    lattr[gid] = s / (float)(deg > 0 ? deg : 1);
}

// ---------------- input MLP: h0 = ELU(x @ W_in + b_in) ----------------

__global__ void in_kernel(const float* __restrict__ x, const float* __restrict__ Wi,
                          const float* __restrict__ bi, float* __restrict__ h0) {
    int gid = blockIdx.x * blockDim.x + threadIdx.x;
    if (gid >= N_NODES * HID) return;
    int n = gid >> 7, j = gid & 127;
    float acc = bi[j];
#pragma unroll
    for (int k = 0; k < IN_F; ++k) acc = fmaf(x[n * IN_F + k], Wi[k * HID + j], acc);
    h0[gid] = elu_f(acc);
}

// ---------------- per-layer node transforms xl = h@Wl+bl (f16), xr = h@Wr+br (f32) ----------------

__global__ __launch_bounds__(128) void xlr_kernel(
    const float* __restrict__ h, const float* __restrict__ Wl, const float* __restrict__ bl,
    const float* __restrict__ Wr, const float* __restrict__ br,
    __half* __restrict__ xl, float* __restrict__ xr) {
    __shared__ float hs[16][HID];
    int t = threadIdx.x;
    int r0 = blockIdx.x * 16;
#pragma unroll
    for (int r = 0; r < 16; ++r) hs[r][t] = h[(size_t)(r0 + r) * HID + t];
    __syncthreads();
    float accl[16], accr[16];
    float blv = bl[t], brv = br[t];
#pragma unroll
    for (int r = 0; r < 16; ++r) { accl[r] = blv; accr[r] = brv; }
    for (int k = 0; k < HID; ++k) {
        float wl = Wl[k * HID + t];
        float wr = Wr[k * HID + t];
#pragma unroll
        for (int r = 0; r < 16; ++r) {
            float hv = hs[r][k];
            accl[r] = fmaf(hv, wl, accl[r]);
            accr[r] = fmaf(hv, wr, accr[r]);
        }
    }
#pragma unroll
    for (int r = 0; r < 16; ++r) {
        xl[(size_t)(r0 + r) * HID + t] = __float2half_rn(accl[r]);
        xr[(size_t)(r0 + r) * HID + t] = accr[r];
    }
}

// ---------------- fused edge kernel: single-pass softmax-aggregate + LN ----------------
// one wave (64 threads) per node; lane l owns channels 2l, 2l+1 (head = l>>4).
// Manual 2-stage software pipeline with named register slots (static indexing).

struct Slot {
    float2 e0, e1, e2;
    __half2 x;
};

__device__ __forceinline__ void slot_issue(Slot& s, const int2* __restrict__ csr, int& pi,
                                           const char* eab, const char* xlb) {
    int2 se = csr[pi]; ++pi;
    const char* eb = eab + (size_t)se.y;
    s.e0 = *(const float2*)eb;
    s.e1 = *(const float2*)(eb + 8);
    s.e2 = *(const float2*)(eb + 16);
    s.x = *(const __half2*)(xlb + (size_t)se.x);
}

__device__ __forceinline__ void slot_consume(const Slot& sl, const float* we0, const float* we1,
                                             float at0, float at1, float xr0, float xr1,
                                             float& denom, float& acc0, float& acc1) {
    float2 xv = __half22float2(sl.x);
    float ea0 = sl.e0.x * we0[0]; ea0 = fmaf(sl.e0.y, we0[1], ea0);
    ea0 = fmaf(sl.e1.x, we0[2], ea0); ea0 = fmaf(sl.e1.y, we0[3], ea0);
    ea0 = fmaf(sl.e2.x, we0[4], ea0); ea0 = fmaf(sl.e2.y, we0[5], ea0);
    float ea1 = sl.e0.x * we1[0]; ea1 = fmaf(sl.e0.y, we1[1], ea1);
    ea1 = fmaf(sl.e1.x, we1[2], ea1); ea1 = fmaf(sl.e1.y, we1[3], ea1);
    ea1 = fmaf(sl.e2.x, we1[4], ea1); ea1 = fmaf(sl.e2.y, we1[5], ea1);
    float m0 = xv.x + xr0 + ea0;
    float m1 = xv.y + xr1 + ea1;
    m0 = m0 > 0.f ? m0 : NEG_SLOPE * m0;
    m1 = m1 > 0.f ? m1 : NEG_SLOPE * m1;
    float t = fmaf(m1, at1, m0 * at0);
    t += __shfl_xor(t, 1);
    t += __shfl_xor(t, 2);
    t += __shfl_xor(t, 4);
    t += __shfl_xor(t, 8);
    float ex = __expf(t);
    denom += ex;
    acc0 = fmaf(ex, xv.x, acc0);
    acc1 = fmaf(ex, xv.y, acc1);
}

__global__ __launch_bounds__(64, 8) void edge_kernel(
    const __half* __restrict__ xl, const float* __restrict__ xr,
    const float* __restrict__ hcur, float* __restrict__ hnext,
    const int* __restrict__ rowptr, const int2* __restrict__ csr,
    const float* __restrict__ eattr, const float* __restrict__ lattr,
    const float* __restrict__ We, const float* __restrict__ att,
    const float* __restrict__ bias_l, const float* __restrict__ lnw,
    const float* __restrict__ lnb) {
    int v = blockIdx.x;
    int lane = threadIdx.x;
    int c0 = lane * 2;

    float we0[ED_F], we1[ED_F];
#pragma unroll
    for (int d = 0; d < ED_F; ++d) {
        float2 w = *(const float2*)(We + d * HID + c0);
        we0[d] = w.x; we1[d] = w.y;
    }
    float2 atv = *(const float2*)(att + c0);
    float at0 = atv.x, at1 = atv.y;
    float2 xrv = *(const float2*)(xr + (size_t)v * HID + c0);
    float xr0 = xrv.x, xr1 = xrv.y;
    int rp0 = rowptr[v], rp1 = rowptr[v + 1];

    const char* xlb = (const char*)xl + (size_t)c0 * 2;  // per-lane base
    const char* eab = (const char*)eattr;

    float denom, acc0, acc1;
    // self-loop
    {
        const float2* la = (const float2*)(lattr + (size_t)v * ED_F);
        Slot sl;
        sl.e0 = la[0]; sl.e1 = la[1]; sl.e2 = la[2];
        sl.x = *(const __half2*)(xlb + (size_t)v * (HID * 2));
        denom = 0.f; acc0 = 0.f; acc1 = 0.f;
        slot_consume(sl, we0, we1, at0, at1, xr0, xr1, denom, acc0, acc1);
    }

    int num = rp1 - rp0;
    int pi = rp0;

    Slot sA, sB;
    if (num > 0) slot_issue(sA, csr, pi, eab, xlb);
    if (num > 1) slot_issue(sB, csr, pi, eab, xlb);
    int j = 0;
    for (; j + 2 <= num; j += 2) {
        slot_consume(sA, we0, we1, at0, at1, xr0, xr1, denom, acc0, acc1);
        if (pi < rp1) slot_issue(sA, csr, pi, eab, xlb);
        slot_consume(sB, we0, we1, at0, at1, xr0, xr1, denom, acc0, acc1);
        if (pi < rp1) slot_issue(sB, csr, pi, eab, xlb);
    }
    if (j < num)
        slot_consume(sA, we0, we1, at0, at1, xr0, xr1, denom, acc0, acc1);

    float rd = 1.f / denom;
    acc0 *= rd;
    acc1 *= rd;

    // ---- epilogue: bias + residual + LayerNorm + ELU
    float2 resv = *(const float2*)(hcur + (size_t)v * HID + c0);
    float2 bv = *(const float2*)(bias_l + c0);
    float y0 = acc0 + bv.x + resv.x;
    float y1 = acc1 + bv.y + resv.y;
    float s = y0 + y1;
    float sq = y0 * y0 + y1 * y1;
#pragma unroll
    for (int off = 1; off < 64; off <<= 1) {
        s += __shfl_xor(s, off);
        sq += __shfl_xor(sq, off);
    }
    float mu = s * (1.f / HID);
    float var = sq * (1.f / HID) - mu * mu;
    float rstd = rsqrtf(var + 1e-5f);
    float2 wv = *(const float2*)(lnw + c0);
    float2 lb = *(const float2*)(lnb + c0);
    float n0 = (y0 - mu) * rstd * wv.x + lb.x;
    float n1 = (y1 - mu) * rstd * wv.y + lb.y;
    float2 o;
    o.x = elu_f(n0);
    o.y = elu_f(n1);
    *(float2*)(hnext + (size_t)v * HID + c0) = o;
}

// ---------------- output GEMM: out = h @ W_out + b_out ----------------

__global__ __launch_bounds__(256) void out_kernel(const float* __restrict__ h,
                                                  const float* __restrict__ Wo,
                                                  const float* __restrict__ bo,
                                                  float* __restrict__ out) {
    __shared__ float hs[16][HID];
    int t = threadIdx.x;
    int r0 = blockIdx.x * 16;
    for (int idx = t; idx < 16 * HID; idx += 256)
        hs[idx >> 7][idx & 127] = h[(size_t)r0 * HID + idx];
    __syncthreads();
    float acc[16];
    float bv = bo[t];
#pragma unroll
    for (int r = 0; r < 16; ++r) acc[r] = bv;
    for (int k = 0; k < HID; ++k) {
        float w = Wo[k * OUT_F + t];
#pragma unroll
        for (int r = 0; r < 16; ++r) acc[r] = fmaf(hs[r][k], w, acc[r]);
    }
#pragma unroll
    for (int r = 0; r < 16; ++r) out[(size_t)(r0 + r) * OUT_F + t] = acc[r];
}

// ---------------- launch ----------------

extern "C" void kernel_launch(void* const* d_in, const int* in_sizes, int n_in,
                              void* d_out, int out_size, void* d_ws, size_t ws_size,
                              hipStream_t stream) {
    const float* x     = (const float*)d_in[0];
    const int*   ei    = (const int*)d_in[1];
    const float* eattr = (const float*)d_in[2];
    const float* W_in  = (const float*)d_in[3];
    const float* b_in  = (const float*)d_in[4];
    const float* W_l   = (const float*)d_in[5];
    const float* b_l   = (const float*)d_in[6];
    const float* W_r   = (const float*)d_in[7];
    const float* b_r   = (const float*)d_in[8];
    const float* W_e   = (const float*)d_in[9];
    const float* att   = (const float*)d_in[10];
    const float* bias  = (const float*)d_in[11];
    const float* lnw   = (const float*)d_in[12];
    const float* lnb   = (const float*)d_in[13];
    const float* W_out = (const float*)d_in[14];
    const float* b_out = (const float*)d_in[15];
    float* out = (float*)d_out;

    // workspace layout
    float* h0    = (float*)d_ws;
    float* h1    = h0 + (size_t)N_NODES * HID;
    float* lattr = h1 + (size_t)N_NODES * HID;
    int* rowptr  = (int*)(lattr + (size_t)N_NODES * ED_F);
    int* fill    = rowptr + (N_NODES + 1);
    int2* csr    = (int2*)(fill + N_NODES);
    int* bsum    = (int*)(csr + N_EDGES);

    // reuse d_out (N x 256 f32) as scratch: xr f32 (N x 128), xl f16 (N x 128);
    // out_kernel fully overwrites it at the end.
    float*  xr = out;
    __half* xl = (__half*)(out + (size_t)N_NODES * HID);

    const int* srcv = ei;
    const int* dstv = ei + N_EDGES;

    hipMemsetAsync(fill, 0, N_NODES * sizeof(int), stream);
    hist_kernel<<<(N_EDGES + 255) / 256, 256, 0, stream>>>(dstv, fill);
    int nb = (N_NODES + 1023) / 1024;
    scan1_kernel<<<nb, 256, 0, stream>>>(fill, bsum);
    scan2_kernel<<<1, 1, 0, stream>>>(bsum, rowptr, nb);
    scan3_kernel<<<nb, 256, 0, stream>>>(fill, bsum, rowptr);
    hipMemsetAsync(fill, 0, N_NODES * sizeof(int), stream);
    fill_kernel<<<(N_EDGES + 255) / 256, 256, 0, stream>>>(srcv, dstv, rowptr, fill, csr);
    lattr_kernel<<<(N_NODES * ED_F + 255) / 256, 256, 0, stream>>>(rowptr, csr, eattr, lattr);

    in_kernel<<<(N_NODES * HID) / 256, 256, 0, stream>>>(x, W_in, b_in, h0);

    float* hc = h0;
    float* hn = h1;
    for (int l = 0; l < LAYERS; ++l) {
        xlr_kernel<<<N_NODES / 16, 128, 0, stream>>>(
            hc, W_l + (size_t)l * HID * HID, b_l + (size_t)l * HID,
            W_r + (size_t)l * HID * HID, b_r + (size_t)l * HID, xl, xr);
        edge_kernel<<<N_NODES, 64, 0, stream>>>(
            xl, xr, hc, hn, rowptr, csr, eattr, lattr,
            W_e + (size_t)l * ED_F * HID, att + (size_t)l * HEADS * CHN,
            bias + (size_t)l * HID, lnw + (size_t)l * HID, lnb + (size_t)l * HID);
        float* tmp = hc; hc = hn; hn = tmp;
    }

    out_kernel<<<N_NODES / 16, 256, 0, stream>>>(hc, W_out, b_out, out);
}

// Round 8
// 1114.790 us; speedup vs baseline: 1.6561x; 1.3049x over previous
//
#include <hip/hip_runtime.h>
#include <hip/hip_bf16.h>
#include <hip/hip_fp16.h>

#define N_NODES 100000
#define N_EDGES 1600000
#define HEADS 4
#define CHN 32
#define HID 128
#define LAYERS 4
#define IN_F 8
#define ED_F 6
#define OUT_F 256
#define NEG_SLOPE 0.2f

typedef _Float16 f16x8 __attribute__((ext_vector_type(8)));
typedef _Float16 f16x4 __attribute__((ext_vector_type(4)));
typedef float f32x4 __attribute__((ext_vector_type(4)));

__device__ __forceinline__ float elu_f(float x) {
    return x > 0.f ? x : expm1f(x);
}

// ---------------- CSR build ----------------

__global__ void hist_kernel(const int* __restrict__ dst, int* __restrict__ fill) {
    int e = blockIdx.x * blockDim.x + threadIdx.x;
    if (e < N_EDGES) atomicAdd(&fill[dst[e]], 1);
}

__global__ void scan1_kernel(const int* __restrict__ cnt, int* __restrict__ bsum) {
    __shared__ int sd[256];
    int t = threadIdx.x;
    int base = blockIdx.x * 1024 + t * 4;
    int s = 0;
#pragma unroll
    for (int j = 0; j < 4; ++j) {
        int i = base + j;
        if (i < N_NODES) s += cnt[i];
    }
    sd[t] = s;
    for (int off = 128; off > 0; off >>= 1) {
        __syncthreads();
        if (t < off) sd[t] += sd[t + off];
    }
    if (t == 0) bsum[blockIdx.x] = sd[0];
}

__global__ void scan2_kernel(int* __restrict__ bsum, int* __restrict__ rowptr, int nb) {
    int run = 0;
    for (int b = 0; b < nb; ++b) {
        int v = bsum[b];
        bsum[b] = run;
        run += v;
    }
    rowptr[N_NODES] = run;
}

__global__ void scan3_kernel(const int* __restrict__ cnt, const int* __restrict__ bsum,
                             int* __restrict__ rowptr) {
    __shared__ int sd[256];
    int t = threadIdx.x;
    int base = blockIdx.x * 1024 + t * 4;
    int v[4];
#pragma unroll
    for (int j = 0; j < 4; ++j) {
        int i = base + j;
        v[j] = (i < N_NODES) ? cnt[i] : 0;
    }
    int s = v[0] + v[1] + v[2] + v[3];
    sd[t] = s;
    __syncthreads();
    for (int off = 1; off < 256; off <<= 1) {
        int xv = (t >= off) ? sd[t - off] : 0;
        __syncthreads();
        sd[t] += xv;
        __syncthreads();
    }
    int excl = sd[t] - s + bsum[blockIdx.x];
    int pre = 0;
#pragma unroll
    for (int j = 0; j < 4; ++j) {
        int i = base + j;
        if (i < N_NODES) rowptr[i] = excl + pre;
        pre += v[j];
    }
}

// csr stores BYTE offsets: x = src*HID*2 (f16 row), y = eid*ED_F*4
__global__ void fill_kernel(const int* __restrict__ src, const int* __restrict__ dst,
                            const int* __restrict__ rowptr, int* __restrict__ fill,
                            int2* __restrict__ csr) {
    int e = blockIdx.x * blockDim.x + threadIdx.x;
    if (e >= N_EDGES) return;
    int d = dst[e];
    int p = rowptr[d] + atomicAdd(&fill[d], 1);
    csr[p] = make_int2(src[e] * (HID * 2), e * (ED_F * 4));
}

// loop_attr = mean of incoming edge_attr per node (0 if no incoming edges)
__global__ void lattr_kernel(const int* __restrict__ rowptr, const int2* __restrict__ csr,
                             const float* __restrict__ eattr, float* __restrict__ lattr) {
    int gid = blockIdx.x * blockDim.x + threadIdx.x;
    if (gid >= N_NODES * ED_F) return;
    int n = gid / ED_F;
    int d = gid - n * ED_F;
    int rp0 = rowptr[n], rp1 = rowptr[n + 1];
    float s = 0.f;
    for (int p = rp0; p < rp1; ++p)
        s += *(const float*)((const char*)eattr + (size_t)csr[p].y + d * 4);
    int deg = rp1 - rp0;
    lattr[gid] = s / (float)(deg > 0 ? deg : 1);
}

// ---------------- weight conversion: build pre-transposed, pre-swizzled f16 panels ---
// 5 buffers of [256 cols][128 k] f16 (65536 B each, XOR-swizzled bytes):
//   b in 0..3: [Wl_b | Wr_b] ; b == 4: W_out

__global__ void convw_kernel(const float* __restrict__ W_l, const float* __restrict__ W_r,
                             const float* __restrict__ W_out, __half* __restrict__ wbt) {
    int gid = blockIdx.x * blockDim.x + threadIdx.x;
    if (gid >= 5 * 256 * 128) return;
    int b = gid >> 15;
    int idx = gid & 32767;
    int n = idx >> 7, k = idx & 127;
    float val;
    if (b < 4)
        val = (n < HID) ? W_l[b * HID * HID + k * HID + n]
                        : W_r[b * HID * HID + k * HID + (n - HID)];
    else
        val = W_out[k * OUT_F + n];
    int boff = n * 256 + ((k * 2) ^ ((n & 7) << 4));
    *(__half*)((char*)wbt + (size_t)b * 65536 + boff) = __float2half_rn(val);
}

// ---------------- input MLP: h0 = ELU(x @ W_in + b_in) ----------------

__global__ void in_kernel(const float* __restrict__ x, const float* __restrict__ Wi,
                          const float* __restrict__ bi, float* __restrict__ h0) {
    int gid = blockIdx.x * blockDim.x + threadIdx.x;
    if (gid >= N_NODES * HID) return;
    int n = gid >> 7, j = gid & 127;
    float acc = bi[j];
#pragma unroll
    for (int k = 0; k < IN_F; ++k) acc = fmaf(x[n * IN_F + k], Wi[k * HID + j], acc);
    h0[gid] = elu_f(acc);
}

// ---------------- MFMA GEMM: [M x 128] f32 (converted to f16) x [128 x 256] f16 ------
// MODE 0: cols 0..127 -> xl16 (f16) with bias0=bl; cols 128..255 -> xr (f32) with bias1=br
// MODE 1: all 256 cols -> outp (f32) with bias0=b_out
// Block: 64 rows x 256 cols, 4 waves (each 64 rows x 64 cols). LDS 80KB -> 2 blocks/CU.

#define LDS_B_OFF 16384

template <int MODE>
__global__ __launch_bounds__(256, 2) void gemm_kernel(
    const float* __restrict__ A, const __half* __restrict__ Bt,
    const float* __restrict__ bias0, const float* __restrict__ bias1,
    __half* __restrict__ xl16, float* __restrict__ xr_out, float* __restrict__ outp) {
    __shared__ __align__(16) unsigned char smem[81920];
    int t = threadIdx.x;
    int row0 = blockIdx.x * 64;

    // stage A: 64 rows x 128 k, f32 -> f16, XOR-swizzled LDS writes
#pragma unroll
    for (int it = 0; it < 8; ++it) {
        int idx = it * 256 + t;
        int r = idx >> 5;
        int k4 = (idx & 31) << 2;
        float4 hv = *(const float4*)(A + (size_t)(row0 + r) * HID + k4);
        f16x4 p;
        p[0] = (_Float16)hv.x; p[1] = (_Float16)hv.y;
        p[2] = (_Float16)hv.z; p[3] = (_Float16)hv.w;
        *(f16x4*)(smem + r * 256 + ((k4 * 2) ^ ((r & 7) << 4))) = p;
    }
    // stage B: pre-swizzled global -> linear LDS copy (65536 B)
#pragma unroll
    for (int it = 0; it < 16; ++it) {
        int off = (it * 256 + t) * 16;
        *(float4*)(smem + LDS_B_OFF + off) = *(const float4*)((const char*)Bt + off);
    }
    __syncthreads();

    int wave = t >> 6;
    int lane = t & 63;
    int lc = lane & 15, lr = lane >> 4;
    int cbase = wave * 64;

    f32x4 acc[4][4];
#pragma unroll
    for (int i = 0; i < 4; ++i)
#pragma unroll
        for (int j = 0; j < 4; ++j) acc[i][j] = (f32x4){0.f, 0.f, 0.f, 0.f};

#pragma unroll
    for (int kk = 0; kk < 4; ++kk) {
        int kb = kk * 64 + lr * 16;  // byte offset of this lane's 8 f16 along K
        f16x8 av[4], bv[4];
#pragma unroll
        for (int rt = 0; rt < 4; ++rt) {
            int r = rt * 16 + lc;
            av[rt] = *(const f16x8*)(smem + r * 256 + (kb ^ ((r & 7) << 4)));
        }
#pragma unroll
        for (int ct = 0; ct < 4; ++ct) {
            int c = cbase + ct * 16 + lc;
            bv[ct] = *(const f16x8*)(smem + LDS_B_OFF + c * 256 + (kb ^ ((c & 7) << 4)));
        }
#pragma unroll
        for (int rt = 0; rt < 4; ++rt)
#pragma unroll
            for (int ct = 0; ct < 4; ++ct)
                acc[rt][ct] = __builtin_amdgcn_mfma_f32_16x16x32_f16(av[rt], bv[ct],
                                                                     acc[rt][ct], 0, 0, 0);
    }

    // epilogue: bias + store (C/D: col = lane&15, row = (lane>>4)*4 + q)
#pragma unroll
    for (int ct = 0; ct < 4; ++ct) {
        int col = cbase + ct * 16 + lc;
        float bv;
        if (MODE == 0) bv = (col < HID) ? bias0[col] : bias1[col - HID];
        else bv = bias0[col];
#pragma unroll
        for (int rt = 0; rt < 4; ++rt) {
#pragma unroll
            for (int q = 0; q < 4; ++q) {
                int node = row0 + rt * 16 + lr * 4 + q;
                if (node < N_NODES) {
                    float val = acc[rt][ct][q] + bv;
                    if (MODE == 0) {
                        if (col < HID)
                            xl16[(size_t)node * HID + col] = __float2half_rn(val);
                        else
                            xr_out[(size_t)node * HID + (col - HID)] = val;
                    } else {
                        outp[(size_t)node * OUT_F + col] = val;
                    }
                }
            }
        }
    }
}

// ---------------- fused edge kernel: single-pass softmax-aggregate + LN ----------------
// one wave (64 threads) per node; lane l owns channels 2l, 2l+1 (head = l>>4).
// Manual 2-stage software pipeline with named register slots (static indexing).

struct Slot {
    float2 e0, e1, e2;
    __half2 x;
};

__device__ __forceinline__ void slot_issue(Slot& s, const int2* __restrict__ csr, int& pi,
                                           const char* eab, const char* xlb) {
    int2 se = csr[pi]; ++pi;
    const char* eb = eab + (size_t)se.y;
    s.e0 = *(const float2*)eb;
    s.e1 = *(const float2*)(eb + 8);
    s.e2 = *(const float2*)(eb + 16);
    s.x = *(const __half2*)(xlb + (size_t)se.x);
}

__device__ __forceinline__ void slot_consume(const Slot& sl, const float* we0, const float* we1,
                                             float at0, float at1, float xr0, float xr1,
                                             float& denom, float& acc0, float& acc1) {
    float2 xv = __half22float2(sl.x);
    float ea0 = sl.e0.x * we0[0]; ea0 = fmaf(sl.e0.y, we0[1], ea0);
    ea0 = fmaf(sl.e1.x, we0[2], ea0); ea0 = fmaf(sl.e1.y, we0[3], ea0);
    ea0 = fmaf(sl.e2.x, we0[4], ea0); ea0 = fmaf(sl.e2.y, we0[5], ea0);
    float ea1 = sl.e0.x * we1[0]; ea1 = fmaf(sl.e0.y, we1[1], ea1);
    ea1 = fmaf(sl.e1.x, we1[2], ea1); ea1 = fmaf(sl.e1.y, we1[3], ea1);
    ea1 = fmaf(sl.e2.x, we1[4], ea1); ea1 = fmaf(sl.e2.y, we1[5], ea1);
    float m0 = xv.x + xr0 + ea0;
    float m1 = xv.y + xr1 + ea1;
    m0 = m0 > 0.f ? m0 : NEG_SLOPE * m0;
    m1 = m1 > 0.f ? m1 : NEG_SLOPE * m1;
    float t = fmaf(m1, at1, m0 * at0);
    t += __shfl_xor(t, 1);
    t += __shfl_xor(t, 2);
    t += __shfl_xor(t, 4);
    t += __shfl_xor(t, 8);
    float ex = __expf(t);
    denom += ex;
    acc0 = fmaf(ex, xv.x, acc0);
    acc1 = fmaf(ex, xv.y, acc1);
}

__global__ __launch_bounds__(64, 8) void edge_kernel(
    const __half* __restrict__ xl, const float* __restrict__ xr,
    const float* __restrict__ hcur, float* __restrict__ hnext,
    const int* __restrict__ rowptr, const int2* __restrict__ csr,
    const float* __restrict__ eattr, const float* __restrict__ lattr,
    const float* __restrict__ We, const float* __restrict__ att,
    const float* __restrict__ bias_l, const float* __restrict__ lnw,
    const float* __restrict__ lnb) {
    int v = blockIdx.x;
    int lane = threadIdx.x;
    int c0 = lane * 2;

    float we0[ED_F], we1[ED_F];
#pragma unroll
    for (int d = 0; d < ED_F; ++d) {
        float2 w = *(const float2*)(We + d * HID + c0);
        we0[d] = w.x; we1[d] = w.y;
    }
    float2 atv = *(const float2*)(att + c0);
    float at0 = atv.x, at1 = atv.y;
    float2 xrv = *(const float2*)(xr + (size_t)v * HID + c0);
    float xr0 = xrv.x, xr1 = xrv.y;
    int rp0 = rowptr[v], rp1 = rowptr[v + 1];

    const char* xlb = (const char*)xl + (size_t)c0 * 2;  // per-lane base
    const char* eab = (const char*)eattr;

    float denom, acc0, acc1;
    // self-loop
    {
        const float2* la = (const float2*)(lattr + (size_t)v * ED_F);
        Slot sl;
        sl.e0 = la[0]; sl.e1 = la[1]; sl.e2 = la[2];
        sl.x = *(const __half2*)(xlb + (size_t)v * (HID * 2));
        denom = 0.f; acc0 = 0.f; acc1 = 0.f;
        slot_consume(sl, we0, we1, at0, at1, xr0, xr1, denom, acc0, acc1);
    }

    int num = rp1 - rp0;
    int pi = rp0;

    Slot sA, sB;
    if (num > 0) slot_issue(sA, csr, pi, eab, xlb);
    if (num > 1) slot_issue(sB, csr, pi, eab, xlb);
    int j = 0;
    for (; j + 2 <= num; j += 2) {
        slot_consume(sA, we0, we1, at0, at1, xr0, xr1, denom, acc0, acc1);
        if (pi < rp1) slot_issue(sA, csr, pi, eab, xlb);
        slot_consume(sB, we0, we1, at0, at1, xr0, xr1, denom, acc0, acc1);
        if (pi < rp1) slot_issue(sB, csr, pi, eab, xlb);
    }
    if (j < num)
        slot_consume(sA, we0, we1, at0, at1, xr0, xr1, denom, acc0, acc1);

    float rd = 1.f / denom;
    acc0 *= rd;
    acc1 *= rd;

    // ---- epilogue: bias + residual + LayerNorm + ELU
    float2 resv = *(const float2*)(hcur + (size_t)v * HID + c0);
    float2 bv = *(const float2*)(bias_l + c0);
    float y0 = acc0 + bv.x + resv.x;
    float y1 = acc1 + bv.y + resv.y;
    float s = y0 + y1;
    float sq = y0 * y0 + y1 * y1;
#pragma unroll
    for (int off = 1; off < 64; off <<= 1) {
        s += __shfl_xor(s, off);
        sq += __shfl_xor(sq, off);
    }
    float mu = s * (1.f / HID);
    float var = sq * (1.f / HID) - mu * mu;
    float rstd = rsqrtf(var + 1e-5f);
    float2 wv = *(const float2*)(lnw + c0);
    float2 lb = *(const float2*)(lnb + c0);
    float n0 = (y0 - mu) * rstd * wv.x + lb.x;
    float n1 = (y1 - mu) * rstd * wv.y + lb.y;
    float2 o;
    o.x = elu_f(n0);
    o.y = elu_f(n1);
    *(float2*)(hnext + (size_t)v * HID + c0) = o;
}

// ---------------- launch ----------------

extern "C" void kernel_launch(void* const* d_in, const int* in_sizes, int n_in,
                              void* d_out, int out_size, void* d_ws, size_t ws_size,
                              hipStream_t stream) {
    const float* x     = (const float*)d_in[0];
    const int*   ei    = (const int*)d_in[1];
    const float* eattr = (const float*)d_in[2];
    const float* W_in  = (const float*)d_in[3];
    const float* b_in  = (const float*)d_in[4];
    const float* W_l   = (const float*)d_in[5];
    const float* b_l   = (const float*)d_in[6];
    const float* W_r   = (const float*)d_in[7];
    const float* b_r   = (const float*)d_in[8];
    const float* W_e   = (const float*)d_in[9];
    const float* att   = (const float*)d_in[10];
    const float* bias  = (const float*)d_in[11];
    const float* lnw   = (const float*)d_in[12];
    const float* lnb   = (const float*)d_in[13];
    const float* W_out = (const float*)d_in[14];
    const float* b_out = (const float*)d_in[15];
    float* out = (float*)d_out;

    // workspace layout
    float* h0    = (float*)d_ws;
    float* h1    = h0 + (size_t)N_NODES * HID;
    float* lattr = h1 + (size_t)N_NODES * HID;
    int* rowptr  = (int*)(lattr + (size_t)N_NODES * ED_F);
    int* fill    = rowptr + (N_NODES + 1);
    int2* csr    = (int2*)(fill + N_NODES);
    int* bsum    = (int*)(csr + N_EDGES);
    __half* wbt  = (__half*)(bsum + 128);   // 5 x 65536 B f16 weight panels

    // reuse d_out (N x 256 f32) as scratch: xr f32 (N x 128), xl f16 (N x 128);
    // final gemm overwrites all of d_out at the end.
    float*  xr = out;
    __half* xl = (__half*)(out + (size_t)N_NODES * HID);

    const int* srcv = ei;
    const int* dstv = ei + N_EDGES;

    hipMemsetAsync(fill, 0, N_NODES * sizeof(int), stream);
    hist_kernel<<<(N_EDGES + 255) / 256, 256, 0, stream>>>(dstv, fill);
    int nb = (N_NODES + 1023) / 1024;
    scan1_kernel<<<nb, 256, 0, stream>>>(fill, bsum);
    scan2_kernel<<<1, 1, 0, stream>>>(bsum, rowptr, nb);
    scan3_kernel<<<nb, 256, 0, stream>>>(fill, bsum, rowptr);
    hipMemsetAsync(fill, 0, N_NODES * sizeof(int), stream);
    fill_kernel<<<(N_EDGES + 255) / 256, 256, 0, stream>>>(srcv, dstv, rowptr, fill, csr);
    lattr_kernel<<<(N_NODES * ED_F + 255) / 256, 256, 0, stream>>>(rowptr, csr, eattr, lattr);

    convw_kernel<<<(5 * 256 * 128 + 255) / 256, 256, 0, stream>>>(W_l, W_r, W_out, wbt);
    in_kernel<<<(N_NODES * HID) / 256, 256, 0, stream>>>(x, W_in, b_in, h0);

    int gemm_grid = (N_NODES + 63) / 64;
    float* hc = h0;
    float* hn = h1;
    for (int l = 0; l < LAYERS; ++l) {
        gemm_kernel<0><<<gemm_grid, 256, 0, stream>>>(
            hc, wbt + (size_t)l * 32768, b_l + (size_t)l * HID, b_r + (size_t)l * HID,
            xl, xr, nullptr);
        edge_kernel<<<N_NODES, 64, 0, stream>>>(
            xl, xr, hc, hn, rowptr, csr, eattr, lattr,
            W_e + (size_t)l * ED_F * HID, att + (size_t)l * HEADS * CHN,
            bias + (size_t)l * HID, lnw + (size_t)l * HID, lnb + (size_t)l * HID);
        float* tmp = hc; hc = hn; hn = tmp;
    }

    gemm_kernel<1><<<gemm_grid, 256, 0, stream>>>(
        hc, wbt + (size_t)4 * 32768, b_out, nullptr, nullptr, nullptr, out);
}

// Round 9
// 1084.443 us; speedup vs baseline: 1.7024x; 1.0280x over previous
//
#include <hip/hip_runtime.h>
#include <hip/hip_bf16.h>
#include <hip/hip_fp16.h>

#define N_NODES 100000
#define N_EDGES 1600000
#define HEADS 4
#define CHN 32
#define HID 128
#define LAYERS 4
#define IN_F 8
#define ED_F 6
#define OUT_F 256
#define NEG_SLOPE 0.2f

typedef _Float16 f16x8 __attribute__((ext_vector_type(8)));
typedef _Float16 f16x4 __attribute__((ext_vector_type(4)));
typedef _Float16 h2 __attribute__((ext_vector_type(2)));
typedef float f32x4 __attribute__((ext_vector_type(4)));

#if defined(__has_builtin)
#if __has_builtin(__builtin_amdgcn_fdot2)
#define HAVE_FDOT2 1
#endif
#endif

__device__ __forceinline__ float elu_f(float x) {
    return x > 0.f ? x : expm1f(x);
}

__device__ __forceinline__ h2 bith2(float f) {
    union { float f; h2 h; } u; u.f = f; return u.h;
}

__device__ __forceinline__ float dot6(h2 e01, h2 e23, h2 e45, const h2* w) {
#ifdef HAVE_FDOT2
    return __builtin_amdgcn_fdot2(e45, w[2],
           __builtin_amdgcn_fdot2(e23, w[1],
           __builtin_amdgcn_fdot2(e01, w[0], 0.f, false), false), false);
#else
    float s = (float)e01[0] * (float)w[0][0];
    s = fmaf((float)e01[1], (float)w[0][1], s);
    s = fmaf((float)e23[0], (float)w[1][0], s);
    s = fmaf((float)e23[1], (float)w[1][1], s);
    s = fmaf((float)e45[0], (float)w[2][0], s);
    s = fmaf((float)e45[1], (float)w[2][1], s);
    return s;
#endif
}

// ---------------- CSR build ----------------

__global__ void hist_kernel(const int* __restrict__ dst, int* __restrict__ fill) {
    int e = blockIdx.x * blockDim.x + threadIdx.x;
    if (e < N_EDGES) atomicAdd(&fill[dst[e]], 1);
}

__global__ void scan1_kernel(const int* __restrict__ cnt, int* __restrict__ bsum) {
    __shared__ int sd[256];
    int t = threadIdx.x;
    int base = blockIdx.x * 1024 + t * 4;
    int s = 0;
#pragma unroll
    for (int j = 0; j < 4; ++j) {
        int i = base + j;
        if (i < N_NODES) s += cnt[i];
    }
    sd[t] = s;
    for (int off = 128; off > 0; off >>= 1) {
        __syncthreads();
        if (t < off) sd[t] += sd[t + off];
    }
    if (t == 0) bsum[blockIdx.x] = sd[0];
}

__global__ void scan2_kernel(int* __restrict__ bsum, int* __restrict__ rowptr, int nb) {
    int run = 0;
    for (int b = 0; b < nb; ++b) {
        int v = bsum[b];
        bsum[b] = run;
        run += v;
    }
    rowptr[N_NODES] = run;
}

__global__ void scan3_kernel(const int* __restrict__ cnt, const int* __restrict__ bsum,
                             int* __restrict__ rowptr) {
    __shared__ int sd[256];
    int t = threadIdx.x;
    int base = blockIdx.x * 1024 + t * 4;
    int v[4];
#pragma unroll
    for (int j = 0; j < 4; ++j) {
        int i = base + j;
        v[j] = (i < N_NODES) ? cnt[i] : 0;
    }
    int s = v[0] + v[1] + v[2] + v[3];
    sd[t] = s;
    __syncthreads();
    for (int off = 1; off < 256; off <<= 1) {
        int xv = (t >= off) ? sd[t - off] : 0;
        __syncthreads();
        sd[t] += xv;
        __syncthreads();
    }
    int excl = sd[t] - s + bsum[blockIdx.x];
    int pre = 0;
#pragma unroll
    for (int j = 0; j < 4; ++j) {
        int i = base + j;
        if (i < N_NODES) rowptr[i] = excl + pre;
        pre += v[j];
    }
}

// csr stores BYTE offsets: x = src*HID*2 (f16 row), y = eid*16 (padded f16 eattr row)
__global__ void fill_kernel(const int* __restrict__ src, const int* __restrict__ dst,
                            const int* __restrict__ rowptr, int* __restrict__ fill,
                            int2* __restrict__ csr) {
    int e = blockIdx.x * blockDim.x + threadIdx.x;
    if (e >= N_EDGES) return;
    int d = dst[e];
    int p = rowptr[d] + atomicAdd(&fill[d], 1);
    csr[p] = make_int2(src[e] * (HID * 2), e * 16);
}

// eattr -> padded f16 [E][8]
__global__ void ecvt_kernel(const float* __restrict__ eattr, __half* __restrict__ ea16) {
    int gid = blockIdx.x * blockDim.x + threadIdx.x;
    if (gid >= N_EDGES * 8) return;
    int e = gid >> 3, d = gid & 7;
    float v = (d < ED_F) ? eattr[e * ED_F + d] : 0.f;
    ea16[gid] = __float2half_rn(v);
}

// loop_attr = mean of incoming edge_attr per node, padded f16 [N][8]
__global__ void lattr_kernel(const int* __restrict__ rowptr, const int2* __restrict__ csr,
                             const float* __restrict__ eattr, __half* __restrict__ lat16) {
    int gid = blockIdx.x * blockDim.x + threadIdx.x;
    if (gid >= N_NODES * 8) return;
    int n = gid >> 3;
    int d = gid & 7;
    float s = 0.f;
    if (d < ED_F) {
        int rp0 = rowptr[n], rp1 = rowptr[n + 1];
        for (int p = rp0; p < rp1; ++p) {
            int eid = csr[p].y >> 4;
            s += eattr[(size_t)eid * ED_F + d];
        }
        int deg = rp1 - rp0;
        s /= (float)(deg > 0 ? deg : 1);
    }
    lat16[gid] = __float2half_rn(s);
}

// ---------------- weight conversion: build pre-transposed, pre-swizzled f16 panels ---

__global__ void convw_kernel(const float* __restrict__ W_l, const float* __restrict__ W_r,
                             const float* __restrict__ W_out, __half* __restrict__ wbt) {
    int gid = blockIdx.x * blockDim.x + threadIdx.x;
    if (gid >= 5 * 256 * 128) return;
    int b = gid >> 15;
    int idx = gid & 32767;
    int n = idx >> 7, k = idx & 127;
    float val;
    if (b < 4)
        val = (n < HID) ? W_l[b * HID * HID + k * HID + n]
                        : W_r[b * HID * HID + k * HID + (n - HID)];
    else
        val = W_out[k * OUT_F + n];
    int boff = n * 256 + ((k * 2) ^ ((n & 7) << 4));
    *(__half*)((char*)wbt + (size_t)b * 65536 + boff) = __float2half_rn(val);
}

// ---------------- input MLP: h0 = ELU(x @ W_in + b_in) ----------------

__global__ void in_kernel(const float* __restrict__ x, const float* __restrict__ Wi,
                          const float* __restrict__ bi, float* __restrict__ h0) {
    int gid = blockIdx.x * blockDim.x + threadIdx.x;
    if (gid >= N_NODES * HID) return;
    int n = gid >> 7, j = gid & 127;
    float acc = bi[j];
#pragma unroll
    for (int k = 0; k < IN_F; ++k) acc = fmaf(x[n * IN_F + k], Wi[k * HID + j], acc);
    h0[gid] = elu_f(acc);
}

// ---------------- MFMA GEMM (unchanged from R8) ----------------

#define LDS_B_OFF 16384

template <int MODE>
__global__ __launch_bounds__(256, 2) void gemm_kernel(
    const float* __restrict__ A, const __half* __restrict__ Bt,
    const float* __restrict__ bias0, const float* __restrict__ bias1,
    __half* __restrict__ xl16, float* __restrict__ xr_out, float* __restrict__ outp) {
    __shared__ __align__(16) unsigned char smem[81920];
    int t = threadIdx.x;
    int row0 = blockIdx.x * 64;

#pragma unroll
    for (int it = 0; it < 8; ++it) {
        int idx = it * 256 + t;
        int r = idx >> 5;
        int k4 = (idx & 31) << 2;
        float4 hv = *(const float4*)(A + (size_t)(row0 + r) * HID + k4);
        f16x4 p;
        p[0] = (_Float16)hv.x; p[1] = (_Float16)hv.y;
        p[2] = (_Float16)hv.z; p[3] = (_Float16)hv.w;
        *(f16x4*)(smem + r * 256 + ((k4 * 2) ^ ((r & 7) << 4))) = p;
    }
#pragma unroll
    for (int it = 0; it < 16; ++it) {
        int off = (it * 256 + t) * 16;
        *(float4*)(smem + LDS_B_OFF + off) = *(const float4*)((const char*)Bt + off);
    }
    __syncthreads();

    int wave = t >> 6;
    int lane = t & 63;
    int lc = lane & 15, lr = lane >> 4;
    int cbase = wave * 64;

    f32x4 acc[4][4];
#pragma unroll
    for (int i = 0; i < 4; ++i)
#pragma unroll
        for (int j = 0; j < 4; ++j) acc[i][j] = (f32x4){0.f, 0.f, 0.f, 0.f};

#pragma unroll
    for (int kk = 0; kk < 4; ++kk) {
        int kb = kk * 64 + lr * 16;
        f16x8 av[4], bv[4];
#pragma unroll
        for (int rt = 0; rt < 4; ++rt) {
            int r = rt * 16 + lc;
            av[rt] = *(const f16x8*)(smem + r * 256 + (kb ^ ((r & 7) << 4)));
        }
#pragma unroll
        for (int ct = 0; ct < 4; ++ct) {
            int c = cbase + ct * 16 + lc;
            bv[ct] = *(const f16x8*)(smem + LDS_B_OFF + c * 256 + (kb ^ ((c & 7) << 4)));
        }
#pragma unroll
        for (int rt = 0; rt < 4; ++rt)
#pragma unroll
            for (int ct = 0; ct < 4; ++ct)
                acc[rt][ct] = __builtin_amdgcn_mfma_f32_16x16x32_f16(av[rt], bv[ct],
                                                                     acc[rt][ct], 0, 0, 0);
    }

#pragma unroll
    for (int ct = 0; ct < 4; ++ct) {
        int col = cbase + ct * 16 + lc;
        float bv;
        if (MODE == 0) bv = (col < HID) ? bias0[col] : bias1[col - HID];
        else bv = bias0[col];
#pragma unroll
        for (int rt = 0; rt < 4; ++rt) {
#pragma unroll
            for (int q = 0; q < 4; ++q) {
                int node = row0 + rt * 16 + lr * 4 + q;
                if (node < N_NODES) {
                    float val = acc[rt][ct][q] + bv;
                    if (MODE == 0) {
                        if (col < HID)
                            xl16[(size_t)node * HID + col] = __float2half_rn(val);
                        else
                            xr_out[(size_t)node * HID + (col - HID)] = val;
                    } else {
                        outp[(size_t)node * OUT_F + col] = val;
                    }
                }
            }
        }
    }
}

// ---------------- fused edge kernel: 2 edges per wave, 4 channels per lane ----------
// One wave per dst node. Half-wave h (lanes 32h..32h+31) processes item i = 2r+h of
// round r; items: 0 = self-loop, i>=1 -> csr[rp0+i-1]. Lane owns channels 4*hl..4*hl+3.
// Halves' partial (acc, denom) combined via shfl_xor(32) at the end.

struct Slot {
    float4 er;   // 8 f16: eattr row (padded)
    float2 xv;   // 4 f16: xl[src] channels c0..c0+3
};

__device__ __forceinline__ void slot_issue(Slot& s, int i, int total, int rp0,
                                           const int2* __restrict__ csr,
                                           const char* eab, const char* lat16v,
                                           const char* xlb, int vbytes) {
    i = min(i, total - 1);
    const char* eb;
    const char* xb;
    if (i == 0) {
        eb = lat16v;
        xb = xlb + (size_t)vbytes;
    } else {
        int2 se = csr[rp0 + i - 1];
        eb = eab + (size_t)se.y;
        xb = xlb + (size_t)se.x;
    }
    s.er = *(const float4*)eb;
    s.xv = *(const float2*)xb;
}

__device__ __forceinline__ void slot_consume(const Slot& sl, int i, int total,
                                             const h2 we_h2[4][3], const float* attv,
                                             const float* xrv,
                                             float& denom, float* acc) {
    h2 e01 = bith2(sl.er.x), e23 = bith2(sl.er.y), e45 = bith2(sl.er.z);
    h2 x01 = bith2(sl.xv.x), x23 = bith2(sl.xv.y);
    float xf[4];
    xf[0] = (float)x01[0]; xf[1] = (float)x01[1];
    xf[2] = (float)x23[0]; xf[3] = (float)x23[1];
    float t = 0.f;
#pragma unroll
    for (int c = 0; c < 4; ++c) {
        float ea = dot6(e01, e23, e45, we_h2[c]);
        float m = xf[c] + xrv[c] + ea;
        m = m > 0.f ? m : NEG_SLOPE * m;
        t = fmaf(m, attv[c], t);
    }
    // head reduce: 8 lanes x 4 ch = 32 channels (stays within half-wave)
    t += __shfl_xor(t, 1);
    t += __shfl_xor(t, 2);
    t += __shfl_xor(t, 4);
    float ex = __expf(t);
    ex = (i < total) ? ex : 0.f;
    denom += ex;
#pragma unroll
    for (int c = 0; c < 4; ++c) acc[c] = fmaf(ex, xf[c], acc[c]);
}

__global__ __launch_bounds__(64, 8) void edge_kernel(
    const __half* __restrict__ xl, const float* __restrict__ xr,
    const float* __restrict__ hcur, float* __restrict__ hnext,
    const int* __restrict__ rowptr, const int2* __restrict__ csr,
    const __half* __restrict__ ea16, const __half* __restrict__ lat16,
    const float* __restrict__ We, const float* __restrict__ att,
    const float* __restrict__ bias_l, const float* __restrict__ lnw,
    const float* __restrict__ lnb) {
    int v = blockIdx.x;
    int lane = threadIdx.x;
    int half = lane >> 5;
    int hl = lane & 31;
    int c0 = hl * 4;

    h2 we_h2[4][3];
#pragma unroll
    for (int c = 0; c < 4; ++c)
#pragma unroll
        for (int d = 0; d < 3; ++d) {
            h2 w;
            w[0] = (_Float16)We[(2 * d) * HID + c0 + c];
            w[1] = (_Float16)We[(2 * d + 1) * HID + c0 + c];
            we_h2[c][d] = w;
        }
    float4 at4 = *(const float4*)(att + c0);
    float attv[4] = {at4.x, at4.y, at4.z, at4.w};
    float4 xr4 = *(const float4*)(xr + (size_t)v * HID + c0);
    float xrv[4] = {xr4.x, xr4.y, xr4.z, xr4.w};

    int rp0 = rowptr[v], rp1 = rowptr[v + 1];
    int total = (rp1 - rp0) + 1;
    int R = (total + 1) >> 1;

    const char* xlb = (const char*)xl + (size_t)c0 * 2;
    const char* eab = (const char*)ea16;
    const char* lat16v = (const char*)lat16 + (size_t)v * 16;
    int vbytes = v * (HID * 2);

    float denom = 0.f;
    float acc[4] = {0.f, 0.f, 0.f, 0.f};

    Slot sA, sB;
    slot_issue(sA, half, total, rp0, csr, eab, lat16v, xlb, vbytes);
    if (R > 1) slot_issue(sB, 2 + half, total, rp0, csr, eab, lat16v, xlb, vbytes);
    int r = 0;
    for (; r + 2 <= R; r += 2) {
        slot_consume(sA, 2 * r + half, total, we_h2, attv, xrv, denom, acc);
        if (r + 2 < R) slot_issue(sA, 2 * (r + 2) + half, total, rp0, csr, eab, lat16v, xlb, vbytes);
        slot_consume(sB, 2 * (r + 1) + half, total, we_h2, attv, xrv, denom, acc);
        if (r + 3 < R) slot_issue(sB, 2 * (r + 3) + half, total, rp0, csr, eab, lat16v, xlb, vbytes);
    }
    if (r < R) slot_consume(sA, 2 * r + half, total, we_h2, attv, xrv, denom, acc);

    // combine halves
    denom += __shfl_xor(denom, 32);
#pragma unroll
    for (int c = 0; c < 4; ++c) acc[c] += __shfl_xor(acc[c], 32);

    float rd = 1.f / denom;

    // ---- epilogue: bias + residual + LayerNorm + ELU (4 channels per lane)
    float4 res4 = *(const float4*)(hcur + (size_t)v * HID + c0);
    float4 bv4 = *(const float4*)(bias_l + c0);
    float y[4];
    y[0] = acc[0] * rd + bv4.x + res4.x;
    y[1] = acc[1] * rd + bv4.y + res4.y;
    y[2] = acc[2] * rd + bv4.z + res4.z;
    y[3] = acc[3] * rd + bv4.w + res4.w;
    float s = y[0] + y[1] + y[2] + y[3];
    float sq = fmaf(y[0], y[0], fmaf(y[1], y[1], fmaf(y[2], y[2], y[3] * y[3])));
#pragma unroll
    for (int off = 1; off < 32; off <<= 1) {
        s += __shfl_xor(s, off);
        sq += __shfl_xor(sq, off);
    }
    float mu = s * (1.f / HID);
    float var = sq * (1.f / HID) - mu * mu;
    float rstd = rsqrtf(var + 1e-5f);
    float4 wv4 = *(const float4*)(lnw + c0);
    float4 lb4 = *(const float4*)(lnb + c0);
    if (half == 0) {
        float4 o;
        o.x = elu_f((y[0] - mu) * rstd * wv4.x + lb4.x);
        o.y = elu_f((y[1] - mu) * rstd * wv4.y + lb4.y);
        o.z = elu_f((y[2] - mu) * rstd * wv4.z + lb4.z);
        o.w = elu_f((y[3] - mu) * rstd * wv4.w + lb4.w);
        *(float4*)(hnext + (size_t)v * HID + c0) = o;
    }
}

// ---------------- launch ----------------

extern "C" void kernel_launch(void* const* d_in, const int* in_sizes, int n_in,
                              void* d_out, int out_size, void* d_ws, size_t ws_size,
                              hipStream_t stream) {
    const float* x     = (const float*)d_in[0];
    const int*   ei    = (const int*)d_in[1];
    const float* eattr = (const float*)d_in[2];
    const float* W_in  = (const float*)d_in[3];
    const float* b_in  = (const float*)d_in[4];
    const float* W_l   = (const float*)d_in[5];
    const float* b_l   = (const float*)d_in[6];
    const float* W_r   = (const float*)d_in[7];
    const float* b_r   = (const float*)d_in[8];
    const float* W_e   = (const float*)d_in[9];
    const float* att   = (const float*)d_in[10];
    const float* bias  = (const float*)d_in[11];
    const float* lnw   = (const float*)d_in[12];
    const float* lnb   = (const float*)d_in[13];
    const float* W_out = (const float*)d_in[14];
    const float* b_out = (const float*)d_in[15];
    float* out = (float*)d_out;

    // workspace layout
    float* h0    = (float*)d_ws;
    float* h1    = h0 + (size_t)N_NODES * HID;
    __half* lat16 = (__half*)(h1 + (size_t)N_NODES * HID);       // N*8 f16
    int* rowptr  = (int*)(lat16 + (size_t)N_NODES * 8);
    int* fill    = rowptr + (N_NODES + 1);
    int2* csr    = (int2*)(fill + N_NODES);
    int* bsum    = (int*)(csr + N_EDGES);
    __half* wbt  = (__half*)(bsum + 128);   // 5 x 65536 B f16 weight panels

    // d_out (N x 256 f32 = 102.4 MB) partition: xr f32 (51.2) | xl f16 (25.6) | ea16 (25.6)
    float*  xr   = out;
    __half* xl   = (__half*)(out + (size_t)N_NODES * HID);
    __half* ea16 = xl + (size_t)N_NODES * HID;   // E*8 f16 = 25.6 MB, fits exactly

    const int* srcv = ei;
    const int* dstv = ei + N_EDGES;

    hipMemsetAsync(fill, 0, N_NODES * sizeof(int), stream);
    hist_kernel<<<(N_EDGES + 255) / 256, 256, 0, stream>>>(dstv, fill);
    int nb = (N_NODES + 1023) / 1024;
    scan1_kernel<<<nb, 256, 0, stream>>>(fill, bsum);
    scan2_kernel<<<1, 1, 0, stream>>>(bsum, rowptr, nb);
    scan3_kernel<<<nb, 256, 0, stream>>>(fill, bsum, rowptr);
    hipMemsetAsync(fill, 0, N_NODES * sizeof(int), stream);
    fill_kernel<<<(N_EDGES + 255) / 256, 256, 0, stream>>>(srcv, dstv, rowptr, fill, csr);
    ecvt_kernel<<<(N_EDGES * 8 + 255) / 256, 256, 0, stream>>>(eattr, ea16);
    lattr_kernel<<<(N_NODES * 8 + 255) / 256, 256, 0, stream>>>(rowptr, csr, eattr, lat16);

    convw_kernel<<<(5 * 256 * 128 + 255) / 256, 256, 0, stream>>>(W_l, W_r, W_out, wbt);
    in_kernel<<<(N_NODES * HID) / 256, 256, 0, stream>>>(x, W_in, b_in, h0);

    int gemm_grid = (N_NODES + 63) / 64;
    float* hc = h0;
    float* hn = h1;
    for (int l = 0; l < LAYERS; ++l) {
        gemm_kernel<0><<<gemm_grid, 256, 0, stream>>>(
            hc, wbt + (size_t)l * 32768, b_l + (size_t)l * HID, b_r + (size_t)l * HID,
            xl, xr, nullptr);
        edge_kernel<<<N_NODES, 64, 0, stream>>>(
            xl, xr, hc, hn, rowptr, csr, ea16, lat16,
            W_e + (size_t)l * ED_F * HID, att + (size_t)l * HEADS * CHN,
            bias + (size_t)l * HID, lnw + (size_t)l * HID, lnb + (size_t)l * HID);
        float* tmp = hc; hc = hn; hn = tmp;
    }

    gemm_kernel<1><<<gemm_grid, 256, 0, stream>>>(
        hc, wbt + (size_t)4 * 32768, b_out, nullptr, nullptr, nullptr, out);
}